// Round 1
// baseline (164.178 us; speedup 1.0000x reference)
//
#include <hip/hip_runtime.h>
#include <math.h>

#define NCLS 15

// ---------------------------------------------------------------------------
// ws layout (floats): ws[0] = sum of loss_elem, ws[1] = num_pos
// ---------------------------------------------------------------------------

__global__ void zero_ws_kernel(float* ws) {
    if (threadIdx.x < 2) ws[threadIdx.x] = 0.0f;
}

__global__ __launch_bounds__(256) void rbox_iou_kernel(
    const float* __restrict__ pred_bboxes,   // (N,4)
    const float* __restrict__ pred_angles,   // (N,1) radians
    const float* __restrict__ target_bboxes, // (N,4)
    const float* __restrict__ target_angles, // (N,1) degrees
    const float* __restrict__ target_scores, // (N,15)
    const int*   __restrict__ fg_mask,       // (N,) bool as int32
    float* __restrict__ ws,
    int n)
{
    const int i = blockIdx.x * blockDim.x + threadIdx.x;
    float loss = 0.0f, cnt = 0.0f;

    if (i < n && fg_mask[i] != 0) {
        cnt = 1.0f;

        const float4 pb = reinterpret_cast<const float4*>(pred_bboxes)[i];
        const float4 tb = reinterpret_cast<const float4*>(target_bboxes)[i];
        const float pa = pred_angles[i];
        // replicate: target_angles / 180.0 * pi
        const float ta = (target_angles[i] / 180.0f) * (float)M_PI;

        // ---- corners (reference _box2corners order) ----
        float c1x[4], c1y[4], c2x[4], c2y[4];
        {
            const float xo[4] = { 0.5f, -0.5f, -0.5f, 0.5f };
            const float yo[4] = { -0.5f, -0.5f, 0.5f, 0.5f };
            float cs = cosf(pa), sn = sinf(pa);
#pragma unroll
            for (int k = 0; k < 4; ++k) {
                float px = pb.z * xo[k], py = pb.w * yo[k];
                c1x[k] = cs * px - sn * py + pb.x;
                c1y[k] = sn * px + cs * py + pb.y;
            }
            cs = cosf(ta); sn = sinf(ta);
#pragma unroll
            for (int k = 0; k < 4; ++k) {
                float px = tb.z * xo[k], py = tb.w * yo[k];
                c2x[k] = cs * px - sn * py + tb.x;
                c2y[k] = sn * px + cs * py + tb.y;
            }
        }

        // ---- 24 candidate vertices: c1(4), c2(4), edge intersections(16) ----
        float vx[24], vy[24];
        bool  vm[24];

        // m1: corners of box1 inside box2
        {
            const float ax = c2x[0], ay = c2y[0];
            const float abx = c2x[1] - ax, aby = c2y[1] - ay;
            const float adx = c2x[3] - ax, ady = c2y[3] - ay;
            const float nab = abx * abx + aby * aby;
            const float nad = adx * adx + ady * ady;
#pragma unroll
            for (int k = 0; k < 4; ++k) {
                float apx = c1x[k] - ax, apy = c1y[k] - ay;
                float pab = apx * abx + apy * aby;
                float pad = apx * adx + apy * ady;
                vx[k] = c1x[k]; vy[k] = c1y[k];
                vm[k] = (pab >= 0.0f) && (pab <= nab) && (pad >= 0.0f) && (pad <= nad);
            }
        }
        // m2: corners of box2 inside box1
        {
            const float ax = c1x[0], ay = c1y[0];
            const float abx = c1x[1] - ax, aby = c1y[1] - ay;
            const float adx = c1x[3] - ax, ady = c1y[3] - ay;
            const float nab = abx * abx + aby * aby;
            const float nad = adx * adx + ady * ady;
#pragma unroll
            for (int k = 0; k < 4; ++k) {
                float apx = c2x[k] - ax, apy = c2y[k] - ay;
                float pab = apx * abx + apy * aby;
                float pad = apx * adx + apy * ady;
                vx[4 + k] = c2x[k]; vy[4 + k] = c2y[k];
                vm[4 + k] = (pab >= 0.0f) && (pab <= nab) && (pad >= 0.0f) && (pad <= nad);
            }
        }
        // edge-pair intersections: slot 8 + a*4 + b (a = box1 edge, b = box2 edge)
#pragma unroll
        for (int a = 0; a < 4; ++a) {
            const float p1x = c1x[a], p1y = c1y[a];
            const float d1x = c1x[(a + 1) & 3] - p1x;
            const float d1y = c1y[(a + 1) & 3] - p1y;
#pragma unroll
            for (int b = 0; b < 4; ++b) {
                const float q1x = c2x[b], q1y = c2y[b];
                const float d2x = c2x[(b + 1) & 3] - q1x;
                const float d2y = c2y[(b + 1) & 3] - q1y;
                const float rx = q1x - p1x, ry = q1y - p1y;
                const float den = d1x * d2y - d1y * d2x;
                const float safe = (fabsf(den) < 1e-12f) ? 1.0f : den;
                const float t = (rx * d2y - ry * d2x) / safe;
                const float u = (rx * d1y - ry * d1x) / safe;
                const bool val = (fabsf(den) > 1e-12f) &&
                                 (t > 0.0f) && (t < 1.0f) &&
                                 (u > 0.0f) && (u < 1.0f);
                const int idx = 8 + a * 4 + b;
                vx[idx] = val ? (p1x + t * d1x) : 0.0f;
                vy[idx] = val ? (p1y + t * d1y) : 0.0f;
                vm[idx] = val;
            }
        }

        // ---- mean of valid vertices (nv = max(count,1)) ----
        float sx = 0.0f, sy = 0.0f, nvf = 0.0f;
#pragma unroll
        for (int k = 0; k < 24; ++k) {
            sx  += vm[k] ? vx[k] : 0.0f;
            sy  += vm[k] ? vy[k] : 0.0f;
            nvf += vm[k] ? 1.0f : 0.0f;
        }
        const float nv = fmaxf(nvf, 1.0f);
        const float mx = sx / nv, my = sy / nv;

        // ---- pseudoangle (monotone with atan2 up to cyclic rotation; shoelace
        //      of a closed polygon is invariant under cyclic rotation) ----
        float ang[24];
#pragma unroll
        for (int k = 0; k < 24; ++k) {
            const float rx = vx[k] - mx, ry = vy[k] - my;
            const float d = fabsf(rx) + fabsf(ry);
            const float a = rx / d;
            float p = (ry >= 0.0f) ? (1.0f - a) : (3.0f + a);
            if (d == 0.0f) p = 0.0f;     // atan2(0,0)=0 analog (nv==1 case)
            ang[k] = vm[k] ? p : INFINITY;
        }

        // ---- global min-key valid vertex (stable: first strict min) ----
        float minA = INFINITY, mnx = 0.0f, mny = 0.0f;
#pragma unroll
        for (int k = 0; k < 24; ++k) {
            const bool t = ang[k] < minA;
            minA = t ? ang[k] : minA;
            mnx  = t ? vx[k]  : mnx;
            mny  = t ? vy[k]  : mny;
        }

        // ---- stable successor scan + shoelace ----
        // key_j > key_i under lexicographic (ang, idx): with a,b compile-time
        // constants after unroll this folds to (>=) for b>a and (>) for b<a.
        float total = 0.0f;
#pragma unroll
        for (int a = 0; a < 24; ++a) {
            const float ai = ang[a];
            float bestA = INFINITY;
            float bx = mnx, by = mny;      // wrap-around fallback
#pragma unroll
            for (int b = 0; b < 24; ++b) {
                if (b == a) continue;
                const float aj = ang[b];
                const bool gt = (b > a) ? (aj >= ai) : (aj > ai);
                const bool take = gt && (aj < bestA);   // first-min = stable
                bestA = take ? aj : bestA;
                bx = take ? vx[b] : bx;
                by = take ? vy[b] : by;
            }
            if (ai < INFINITY)
                total += vx[a] * by - bx * vy[a];
        }
        const float inter = 0.5f * fabsf(total);

        const float area1 = pb.z * pb.w;
        const float area2 = tb.z * tb.w;
        float iou = inter / (area1 + area2 - inter + 1e-9f);
        iou = fmaxf(iou, 0.1f);

        float w = 0.0f;
#pragma unroll
        for (int k = 0; k < NCLS; ++k) w += target_scores[i * NCLS + k];

        loss = (1.0f - iou) * w;
    }

    // ---- block reduction: wave shuffle (width 64) -> LDS -> 2 atomics ----
#pragma unroll
    for (int off = 32; off > 0; off >>= 1) {
        loss += __shfl_down(loss, off, 64);
        cnt  += __shfl_down(cnt,  off, 64);
    }
    __shared__ float sl[4], sc[4];
    const int lane = threadIdx.x & 63;
    const int wid  = threadIdx.x >> 6;
    if (lane == 0) { sl[wid] = loss; sc[wid] = cnt; }
    __syncthreads();
    if (threadIdx.x == 0) {
        const float L = sl[0] + sl[1] + sl[2] + sl[3];
        const float C = sc[0] + sc[1] + sc[2] + sc[3];
        atomicAdd(&ws[0], L);
        atomicAdd(&ws[1], C);
    }
}

__global__ void finalize_kernel(const float* __restrict__ ws,
                                const float* __restrict__ tss,
                                float* __restrict__ out)
{
    const float lsum = ws[0];
    const float npos = ws[1];
    const float lmean = lsum / fmaxf(npos, 1.0f);
    float li = (tss[0] == 0.0f) ? lsum : lmean;
    li = (npos > 0.0f) ? li : 0.0f;
    out[0] = li;
    out[1] = 0.0f;   // loss_dfl = pred_dist.sum() * 0.0
}

extern "C" void kernel_launch(void* const* d_in, const int* in_sizes, int n_in,
                              void* d_out, int out_size, void* d_ws, size_t ws_size,
                              hipStream_t stream) {
    // input order per setup_inputs():
    // 0 pred_dist (unused), 1 pred_bboxes, 2 pred_angles, 3 anchor_points (unused),
    // 4 target_bboxes, 5 target_angles, 6 target_scores, 7 target_scores_sum, 8 fg_mask
    const float* pred_bboxes   = (const float*)d_in[1];
    const float* pred_angles   = (const float*)d_in[2];
    const float* target_bboxes = (const float*)d_in[4];
    const float* target_angles = (const float*)d_in[5];
    const float* target_scores = (const float*)d_in[6];
    const float* tss           = (const float*)d_in[7];
    const int*   fg_mask       = (const int*)d_in[8];

    float* ws  = (float*)d_ws;
    float* out = (float*)d_out;

    const int n = in_sizes[8];   // B*L = 268800
    const int blocks = (n + 255) / 256;

    zero_ws_kernel<<<1, 64, 0, stream>>>(ws);
    rbox_iou_kernel<<<blocks, 256, 0, stream>>>(
        pred_bboxes, pred_angles, target_bboxes, target_angles,
        target_scores, fg_mask, ws, n);
    finalize_kernel<<<1, 1, 0, stream>>>(ws, tss, out);
}

// Round 2
// 152.348 us; speedup vs baseline: 1.0777x; 1.0777x over previous
//
#include <hip/hip_runtime.h>
#include <math.h>

#define NCLS 15
#define NV 24

// ---------------------------------------------------------------------------
// ws layout:
//   float ws[0]          : loss sum accumulator
//   int   ((int*)ws)[1]  : positive count (compaction counter == num_pos)
//   int*  idxbuf = (int*)ws + 16 : compacted positive indices (worst case N)
// ---------------------------------------------------------------------------

__global__ void zero_ws_kernel(float* ws) {
    if (threadIdx.x == 0) { ws[0] = 0.0f; ((int*)ws)[1] = 0; }
}

// ---- pass 1: compact indices of fg_mask != 0 ------------------------------
__global__ __launch_bounds__(256) void compact_kernel(
    const int* __restrict__ fg_mask, int n,
    int* __restrict__ cnt, int* __restrict__ idxbuf)
{
    const int i = blockIdx.x * 256 + threadIdx.x;
    const bool pos = (i < n) && (fg_mask[i] != 0);
    const unsigned long long b = __ballot(pos);
    const int lane = threadIdx.x & 63;
    const int wid  = threadIdx.x >> 6;
    const int prefix = __popcll(b & ((1ULL << lane) - 1ULL));
    const int wtotal = __popcll(b);

    __shared__ int wbase[4];
    if (lane == 0) wbase[wid] = wtotal;
    __syncthreads();
    if (threadIdx.x == 0) {
        const int t0 = wbase[0], t1 = wbase[1], t2 = wbase[2], t3 = wbase[3];
        const int base = atomicAdd(cnt, t0 + t1 + t2 + t3);
        wbase[0] = base;
        wbase[1] = base + t0;
        wbase[2] = base + t0 + t1;
        wbase[3] = base + t0 + t1 + t2;
    }
    __syncthreads();
    if (pos) idxbuf[wbase[wid] + prefix] = i;
}

// ---- pass 2: heavy IoU on packed indices ----------------------------------
#define CSWAP(A, B)                                                       \
    {                                                                     \
        const float ka = ang[A], kb = ang[B];                             \
        const bool sw = kb < ka;                                          \
        ang[A] = sw ? kb : ka; ang[B] = sw ? ka : kb;                     \
        const float xa = vx[A], xb = vx[B];                               \
        vx[A] = sw ? xb : xa; vx[B] = sw ? xa : xb;                       \
        const float ya = vy[A], yb = vy[B];                               \
        vy[A] = sw ? yb : ya; vy[B] = sw ? ya : yb;                       \
    }

__global__ __launch_bounds__(256) void rbox_iou_kernel(
    const float* __restrict__ pred_bboxes,   // (N,4)
    const float* __restrict__ pred_angles,   // (N,1) radians
    const float* __restrict__ target_bboxes, // (N,4)
    const float* __restrict__ target_angles, // (N,1) degrees
    const float* __restrict__ target_scores, // (N,15)
    const int*   __restrict__ cnt,
    const int*   __restrict__ idxbuf,
    float* __restrict__ ws)
{
    const int count = *cnt;
    if ((int)(blockIdx.x * 256) >= count) return;   // block-uniform early exit

    const int j = blockIdx.x * 256 + threadIdx.x;
    float loss = 0.0f;

    if (j < count) {
        const int i = idxbuf[j];

        const float4 pb = reinterpret_cast<const float4*>(pred_bboxes)[i];
        const float4 tb = reinterpret_cast<const float4*>(target_bboxes)[i];
        const float pa = pred_angles[i];
        const float ta = (target_angles[i] / 180.0f) * (float)M_PI;

        // ---- corners (reference _box2corners order) ----
        float c1x[4], c1y[4], c2x[4], c2y[4];
        {
            const float xo[4] = { 0.5f, -0.5f, -0.5f, 0.5f };
            const float yo[4] = { -0.5f, -0.5f, 0.5f, 0.5f };
            float cs = cosf(pa), sn = sinf(pa);
#pragma unroll
            for (int k = 0; k < 4; ++k) {
                const float px = pb.z * xo[k], py = pb.w * yo[k];
                c1x[k] = cs * px - sn * py + pb.x;
                c1y[k] = sn * px + cs * py + pb.y;
            }
            cs = cosf(ta); sn = sinf(ta);
#pragma unroll
            for (int k = 0; k < 4; ++k) {
                const float px = tb.z * xo[k], py = tb.w * yo[k];
                c2x[k] = cs * px - sn * py + tb.x;
                c2y[k] = sn * px + cs * py + tb.y;
            }
        }

        float vx[NV], vy[NV];
        bool  vm[NV];

        // corners of box1 inside box2
        {
            const float ax = c2x[0], ay = c2y[0];
            const float abx = c2x[1] - ax, aby = c2y[1] - ay;
            const float adx = c2x[3] - ax, ady = c2y[3] - ay;
            const float nab = abx * abx + aby * aby;
            const float nad = adx * adx + ady * ady;
#pragma unroll
            for (int k = 0; k < 4; ++k) {
                const float apx = c1x[k] - ax, apy = c1y[k] - ay;
                const float pab = apx * abx + apy * aby;
                const float pad = apx * adx + apy * ady;
                vx[k] = c1x[k]; vy[k] = c1y[k];
                vm[k] = (pab >= 0.0f) && (pab <= nab) && (pad >= 0.0f) && (pad <= nad);
            }
        }
        // corners of box2 inside box1
        {
            const float ax = c1x[0], ay = c1y[0];
            const float abx = c1x[1] - ax, aby = c1y[1] - ay;
            const float adx = c1x[3] - ax, ady = c1y[3] - ay;
            const float nab = abx * abx + aby * aby;
            const float nad = adx * adx + ady * ady;
#pragma unroll
            for (int k = 0; k < 4; ++k) {
                const float apx = c2x[k] - ax, apy = c2y[k] - ay;
                const float pab = apx * abx + apy * aby;
                const float pad = apx * adx + apy * ady;
                vx[4 + k] = c2x[k]; vy[4 + k] = c2y[k];
                vm[4 + k] = (pab >= 0.0f) && (pab <= nab) && (pad >= 0.0f) && (pad <= nad);
            }
        }
        // edge-pair intersections
#pragma unroll
        for (int a = 0; a < 4; ++a) {
            const float p1x = c1x[a], p1y = c1y[a];
            const float d1x = c1x[(a + 1) & 3] - p1x;
            const float d1y = c1y[(a + 1) & 3] - p1y;
#pragma unroll
            for (int b = 0; b < 4; ++b) {
                const float q1x = c2x[b], q1y = c2y[b];
                const float d2x = c2x[(b + 1) & 3] - q1x;
                const float d2y = c2y[(b + 1) & 3] - q1y;
                const float rx = q1x - p1x, ry = q1y - p1y;
                const float den = d1x * d2y - d1y * d2x;
                const float safe = (fabsf(den) < 1e-12f) ? 1.0f : den;
                const float t = (rx * d2y - ry * d2x) / safe;
                const float u = (rx * d1y - ry * d1x) / safe;
                const bool val = (fabsf(den) > 1e-12f) &&
                                 (t > 0.0f) && (t < 1.0f) &&
                                 (u > 0.0f) && (u < 1.0f);
                const int idx = 8 + a * 4 + b;
                vx[idx] = val ? (p1x + t * d1x) : 0.0f;
                vy[idx] = val ? (p1y + t * d1y) : 0.0f;
                vm[idx] = val;
            }
        }

        // ---- mean of valid vertices ----
        float sx = 0.0f, sy = 0.0f, nvf = 0.0f;
#pragma unroll
        for (int k = 0; k < NV; ++k) {
            sx  += vm[k] ? vx[k] : 0.0f;
            sy  += vm[k] ? vy[k] : 0.0f;
            nvf += vm[k] ? 1.0f : 0.0f;
        }
        const float nv = fmaxf(nvf, 1.0f);
        const float mx = sx / nv, my = sy / nv;

        // ---- pseudoangle keys (cyclic order == atan2 order up to rotation;
        //      shoelace of a closed polygon is rotation-invariant) ----
        float ang[NV];
#pragma unroll
        for (int k = 0; k < NV; ++k) {
            const float rx = vx[k] - mx, ry = vy[k] - my;
            const float d = fabsf(rx) + fabsf(ry);
            const float a = rx / d;
            float p = (ry >= 0.0f) ? (1.0f - a) : (3.0f + a);
            if (d == 0.0f) p = 0.0f;     // atan2(0,0)=0 analog
            ang[k] = vm[k] ? p : INFINITY;
        }

        // ---- Batcher odd-even mergesort, n=32 pruned to 24 (compile-time
        //      indices after full unroll -> arrays stay in VGPRs) ----
#pragma unroll
        for (int p = 1; p < 32; p <<= 1) {
#pragma unroll
            for (int k = p; k >= 1; k >>= 1) {
#pragma unroll
                for (int jj = k & (p - 1); jj + k < 32; jj += 2 * k) {
#pragma unroll
                    for (int ii = 0; ii < k; ++ii) {
                        if (ii + jj + k < 32 &&
                            ((ii + jj) / (2 * p)) == ((ii + jj + k) / (2 * p))) {
                            if (ii + jj + k < NV) {
                                CSWAP(ii + jj, ii + jj + k);
                            }
                        }
                    }
                }
            }
        }

        // ---- shoelace over sorted valid prefix (invalid = +INF at end).
        // Matches reference's where(sm, sv, sv[:1]) + full cyclic sum:
        // trailing invalid slots contribute cross(v0,v0)=0. ----
        const float v0x = vx[0], v0y = vy[0];
        float total = 0.0f;
#pragma unroll
        for (int k = 0; k < NV; ++k) {
            const bool vk = ang[k] < INFINITY;
            const bool vn = (k < NV - 1) ? (ang[k + 1] < INFINITY) : false;
            const float nx = vn ? vx[k + 1] : v0x;
            const float ny = vn ? vy[k + 1] : v0y;
            total += vk ? (vx[k] * ny - nx * vy[k]) : 0.0f;
        }
        const float inter = 0.5f * fabsf(total);

        const float area1 = pb.z * pb.w;
        const float area2 = tb.z * tb.w;
        float iou = inter / (area1 + area2 - inter + 1e-9f);
        iou = fmaxf(iou, 0.1f);

        float w = 0.0f;
        const float* sp = target_scores + (size_t)i * NCLS;
#pragma unroll
        for (int k = 0; k < NCLS; ++k) w += sp[k];

        loss = (1.0f - iou) * w;
    }

    // ---- block reduction -> 1 atomic ----
#pragma unroll
    for (int off = 32; off > 0; off >>= 1)
        loss += __shfl_down(loss, off, 64);
    __shared__ float sl[4];
    const int lane = threadIdx.x & 63;
    const int wid  = threadIdx.x >> 6;
    if (lane == 0) sl[wid] = loss;
    __syncthreads();
    if (threadIdx.x == 0)
        atomicAdd(&ws[0], sl[0] + sl[1] + sl[2] + sl[3]);
}

__global__ void finalize_kernel(const float* __restrict__ ws,
                                const float* __restrict__ tss,
                                float* __restrict__ out)
{
    const float lsum = ws[0];
    const float npos = (float)((const int*)ws)[1];
    const float lmean = lsum / fmaxf(npos, 1.0f);
    float li = (tss[0] == 0.0f) ? lsum : lmean;
    li = (npos > 0.0f) ? li : 0.0f;
    out[0] = li;
    out[1] = 0.0f;   // loss_dfl = pred_dist.sum() * 0.0
}

extern "C" void kernel_launch(void* const* d_in, const int* in_sizes, int n_in,
                              void* d_out, int out_size, void* d_ws, size_t ws_size,
                              hipStream_t stream) {
    // inputs: 0 pred_dist (unused), 1 pred_bboxes, 2 pred_angles,
    // 3 anchor_points (unused), 4 target_bboxes, 5 target_angles,
    // 6 target_scores, 7 target_scores_sum, 8 fg_mask
    const float* pred_bboxes   = (const float*)d_in[1];
    const float* pred_angles   = (const float*)d_in[2];
    const float* target_bboxes = (const float*)d_in[4];
    const float* target_angles = (const float*)d_in[5];
    const float* target_scores = (const float*)d_in[6];
    const float* tss           = (const float*)d_in[7];
    const int*   fg_mask       = (const int*)d_in[8];

    float* ws     = (float*)d_ws;
    int*   cnt    = (int*)d_ws + 1;
    int*   idxbuf = (int*)d_ws + 16;
    float* out    = (float*)d_out;

    const int n = in_sizes[8];               // B*L = 268800
    const int blocks = (n + 255) / 256;      // 1050

    zero_ws_kernel<<<1, 64, 0, stream>>>(ws);
    compact_kernel<<<blocks, 256, 0, stream>>>(fg_mask, n, cnt, idxbuf);
    rbox_iou_kernel<<<blocks, 256, 0, stream>>>(
        pred_bboxes, pred_angles, target_bboxes, target_angles,
        target_scores, cnt, idxbuf, ws);
    finalize_kernel<<<1, 1, 0, stream>>>(ws, tss, out);
}

// Round 3
// 145.697 us; speedup vs baseline: 1.1268x; 1.0457x over previous
//
#include <hip/hip_runtime.h>
#include <math.h>

#define NCLS 15
#define NV 24
#define EPB 1024   // elements per block (256 threads x 4)

// ---------------------------------------------------------------------------
// ws layout (16B, memset to 0 each launch):
//   float ws[0] : loss sum accumulator
//   int   ws[1] : positive count
//   int   ws[2] : blocks-done counter
// ---------------------------------------------------------------------------

#define CSWAP(A, B)                                                       \
    {                                                                     \
        const float ka = ang[A], kb = ang[B];                             \
        const bool sw = kb < ka;                                          \
        ang[A] = sw ? kb : ka; ang[B] = sw ? ka : kb;                     \
        const float xa = vx[A], xb = vx[B];                               \
        vx[A] = sw ? xb : xa; vx[B] = sw ? xa : xb;                       \
        const float ya = vy[A], yb = vy[B];                               \
        vy[A] = sw ? yb : ya; vy[B] = sw ? ya : yb;                       \
    }

__device__ __forceinline__ float elem_loss(
    int i,
    const float* __restrict__ pred_bboxes,
    const float* __restrict__ pred_angles,
    const float* __restrict__ target_bboxes,
    const float* __restrict__ target_angles,
    const float* __restrict__ target_scores)
{
    const float4 pb = reinterpret_cast<const float4*>(pred_bboxes)[i];
    const float4 tb = reinterpret_cast<const float4*>(target_bboxes)[i];
    const float pa = pred_angles[i];
    const float ta = (target_angles[i] / 180.0f) * (float)M_PI;

    // ---- corners (reference _box2corners order) ----
    float c1x[4], c1y[4], c2x[4], c2y[4];
    {
        const float xo[4] = { 0.5f, -0.5f, -0.5f, 0.5f };
        const float yo[4] = { -0.5f, -0.5f, 0.5f, 0.5f };
        float cs = cosf(pa), sn = sinf(pa);
#pragma unroll
        for (int k = 0; k < 4; ++k) {
            const float px = pb.z * xo[k], py = pb.w * yo[k];
            c1x[k] = cs * px - sn * py + pb.x;
            c1y[k] = sn * px + cs * py + pb.y;
        }
        cs = cosf(ta); sn = sinf(ta);
#pragma unroll
        for (int k = 0; k < 4; ++k) {
            const float px = tb.z * xo[k], py = tb.w * yo[k];
            c2x[k] = cs * px - sn * py + tb.x;
            c2y[k] = sn * px + cs * py + tb.y;
        }
    }

    float vx[NV], vy[NV];
    bool  vm[NV];

    // corners of box1 inside box2
    {
        const float ax = c2x[0], ay = c2y[0];
        const float abx = c2x[1] - ax, aby = c2y[1] - ay;
        const float adx = c2x[3] - ax, ady = c2y[3] - ay;
        const float nab = abx * abx + aby * aby;
        const float nad = adx * adx + ady * ady;
#pragma unroll
        for (int k = 0; k < 4; ++k) {
            const float apx = c1x[k] - ax, apy = c1y[k] - ay;
            const float pab = apx * abx + apy * aby;
            const float pad = apx * adx + apy * ady;
            vx[k] = c1x[k]; vy[k] = c1y[k];
            vm[k] = (pab >= 0.0f) && (pab <= nab) && (pad >= 0.0f) && (pad <= nad);
        }
    }
    // corners of box2 inside box1
    {
        const float ax = c1x[0], ay = c1y[0];
        const float abx = c1x[1] - ax, aby = c1y[1] - ay;
        const float adx = c1x[3] - ax, ady = c1y[3] - ay;
        const float nab = abx * abx + aby * aby;
        const float nad = adx * adx + ady * ady;
#pragma unroll
        for (int k = 0; k < 4; ++k) {
            const float apx = c2x[k] - ax, apy = c2y[k] - ay;
            const float pab = apx * abx + apy * aby;
            const float pad = apx * adx + apy * ady;
            vx[4 + k] = c2x[k]; vy[4 + k] = c2y[k];
            vm[4 + k] = (pab >= 0.0f) && (pab <= nab) && (pad >= 0.0f) && (pad <= nad);
        }
    }
    // edge-pair intersections
#pragma unroll
    for (int a = 0; a < 4; ++a) {
        const float p1x = c1x[a], p1y = c1y[a];
        const float d1x = c1x[(a + 1) & 3] - p1x;
        const float d1y = c1y[(a + 1) & 3] - p1y;
#pragma unroll
        for (int b = 0; b < 4; ++b) {
            const float q1x = c2x[b], q1y = c2y[b];
            const float d2x = c2x[(b + 1) & 3] - q1x;
            const float d2y = c2y[(b + 1) & 3] - q1y;
            const float rx = q1x - p1x, ry = q1y - p1y;
            const float den = d1x * d2y - d1y * d2x;
            const float safe = (fabsf(den) < 1e-12f) ? 1.0f : den;
            const float t = (rx * d2y - ry * d2x) / safe;
            const float u = (rx * d1y - ry * d1x) / safe;
            const bool val = (fabsf(den) > 1e-12f) &&
                             (t > 0.0f) && (t < 1.0f) &&
                             (u > 0.0f) && (u < 1.0f);
            const int idx = 8 + a * 4 + b;
            vx[idx] = val ? (p1x + t * d1x) : 0.0f;
            vy[idx] = val ? (p1y + t * d1y) : 0.0f;
            vm[idx] = val;
        }
    }

    // ---- mean of valid vertices ----
    float sx = 0.0f, sy = 0.0f, nvf = 0.0f;
#pragma unroll
    for (int k = 0; k < NV; ++k) {
        sx  += vm[k] ? vx[k] : 0.0f;
        sy  += vm[k] ? vy[k] : 0.0f;
        nvf += vm[k] ? 1.0f : 0.0f;
    }
    const float nv = fmaxf(nvf, 1.0f);
    const float mx = sx / nv, my = sy / nv;

    // ---- pseudoangle keys (cyclic order == atan2 order up to rotation;
    //      shoelace of a closed polygon is rotation-invariant) ----
    float ang[NV];
#pragma unroll
    for (int k = 0; k < NV; ++k) {
        const float rx = vx[k] - mx, ry = vy[k] - my;
        const float d = fabsf(rx) + fabsf(ry);
        const float a = rx / d;
        float p = (ry >= 0.0f) ? (1.0f - a) : (3.0f + a);
        if (d == 0.0f) p = 0.0f;     // atan2(0,0)=0 analog
        ang[k] = vm[k] ? p : INFINITY;
    }

    // ---- Batcher odd-even mergesort, n=32 pruned to 24 (compile-time
    //      indices after full unroll -> arrays stay in VGPRs) ----
#pragma unroll
    for (int p = 1; p < 32; p <<= 1) {
#pragma unroll
        for (int k = p; k >= 1; k >>= 1) {
#pragma unroll
            for (int jj = k & (p - 1); jj + k < 32; jj += 2 * k) {
#pragma unroll
                for (int ii = 0; ii < k; ++ii) {
                    if (ii + jj + k < 32 &&
                        ((ii + jj) / (2 * p)) == ((ii + jj + k) / (2 * p))) {
                        if (ii + jj + k < NV) {
                            CSWAP(ii + jj, ii + jj + k);
                        }
                    }
                }
            }
        }
    }

    // ---- shoelace over sorted valid prefix (invalid = +INF at end).
    // Matches reference's where(sm, sv, sv[:1]) + full cyclic sum:
    // trailing invalid slots contribute cross(v0,v0)=0. ----
    const float v0x = vx[0], v0y = vy[0];
    float total = 0.0f;
#pragma unroll
    for (int k = 0; k < NV; ++k) {
        const bool vk = ang[k] < INFINITY;
        const bool vn = (k < NV - 1) ? (ang[k + 1] < INFINITY) : false;
        const float nx = vn ? vx[k + 1] : v0x;
        const float ny = vn ? vy[k + 1] : v0y;
        total += vk ? (vx[k] * ny - nx * vy[k]) : 0.0f;
    }
    const float inter = 0.5f * fabsf(total);

    const float area1 = pb.z * pb.w;
    const float area2 = tb.z * tb.w;
    float iou = inter / (area1 + area2 - inter + 1e-9f);
    iou = fmaxf(iou, 0.1f);

    float w = 0.0f;
    const float* sp = target_scores + (size_t)i * NCLS;
#pragma unroll
    for (int k = 0; k < NCLS; ++k) w += sp[k];

    return (1.0f - iou) * w;
}

__global__ __launch_bounds__(256) void fused_loss_kernel(
    const float* __restrict__ pred_bboxes,   // (N,4)
    const float* __restrict__ pred_angles,   // (N,1) radians
    const float* __restrict__ target_bboxes, // (N,4)
    const float* __restrict__ target_angles, // (N,1) degrees
    const float* __restrict__ target_scores, // (N,15)
    const int*   __restrict__ fg_mask,       // (N,)
    const float* __restrict__ tss,           // (1,)
    float* __restrict__ ws,                  // [0]=loss sum, [1]=count, [2]=done
    float* __restrict__ out,                 // [0]=loss_iou, [1]=loss_dfl
    int n, int nblocks)
{
    __shared__ int sidx[EPB];
    __shared__ int scnt;
    __shared__ float sl[4];
    __shared__ bool slast;

    const int tid = threadIdx.x;
    if (tid == 0) scnt = 0;
    __syncthreads();

    // ---- block-local compaction: 1024 elems -> ~256 positive indices ----
    const int base = blockIdx.x * EPB + tid * 4;
    if (base < n) {   // n % 4 == 0 -> all-or-nothing per thread
        const int4 m = *reinterpret_cast<const int4*>(fg_mask + base);
        if (m.x) sidx[atomicAdd(&scnt, 1)] = base + 0;
        if (m.y) sidx[atomicAdd(&scnt, 1)] = base + 1;
        if (m.z) sidx[atomicAdd(&scnt, 1)] = base + 2;
        if (m.w) sidx[atomicAdd(&scnt, 1)] = base + 3;
    }
    __syncthreads();
    const int lcnt = scnt;

    // ---- full-lane heavy body over compacted list ----
    float loss = 0.0f;
    for (int k = tid; k < lcnt; k += 256)
        loss += elem_loss(sidx[k], pred_bboxes, pred_angles,
                          target_bboxes, target_angles, target_scores);

    // ---- block reduce -> device atomics ----
#pragma unroll
    for (int off = 32; off > 0; off >>= 1)
        loss += __shfl_down(loss, off, 64);
    const int lane = tid & 63;
    const int wid  = tid >> 6;
    if (lane == 0) sl[wid] = loss;
    __syncthreads();
    if (tid == 0) {
        atomicAdd(&ws[0], sl[0] + sl[1] + sl[2] + sl[3]);
        atomicAdd((int*)ws + 1, lcnt);
        __threadfence();
        const int done = atomicAdd((int*)ws + 2, 1);
        slast = (done == nblocks - 1);
    }
    __syncthreads();

    // ---- last block finalizes (device-scope atomic reads) ----
    if (slast && tid == 0) {
        const float lsum = atomicAdd(&ws[0], 0.0f);
        const float npos = (float)atomicAdd((int*)ws + 1, 0);
        const float lmean = lsum / fmaxf(npos, 1.0f);
        float li = (tss[0] == 0.0f) ? lsum : lmean;
        li = (npos > 0.0f) ? li : 0.0f;
        out[0] = li;
        out[1] = 0.0f;   // loss_dfl = pred_dist.sum() * 0.0
    }
}

extern "C" void kernel_launch(void* const* d_in, const int* in_sizes, int n_in,
                              void* d_out, int out_size, void* d_ws, size_t ws_size,
                              hipStream_t stream) {
    // inputs: 0 pred_dist (unused), 1 pred_bboxes, 2 pred_angles,
    // 3 anchor_points (unused), 4 target_bboxes, 5 target_angles,
    // 6 target_scores, 7 target_scores_sum, 8 fg_mask
    const float* pred_bboxes   = (const float*)d_in[1];
    const float* pred_angles   = (const float*)d_in[2];
    const float* target_bboxes = (const float*)d_in[4];
    const float* target_angles = (const float*)d_in[5];
    const float* target_scores = (const float*)d_in[6];
    const float* tss           = (const float*)d_in[7];
    const int*   fg_mask       = (const int*)d_in[8];

    float* ws  = (float*)d_ws;
    float* out = (float*)d_out;

    const int n = in_sizes[8];                 // B*L = 268800
    const int blocks = (n + EPB - 1) / EPB;    // 263

    hipMemsetAsync(d_ws, 0, 16, stream);       // ws[0..3] = 0
    fused_loss_kernel<<<blocks, 256, 0, stream>>>(
        pred_bboxes, pred_angles, target_bboxes, target_angles,
        target_scores, fg_mask, tss, ws, out, n, blocks);
}